// Round 3
// baseline (342.492 us; speedup 1.0000x reference)
//
#include <hip/hip_runtime.h>
#include <stdint.h>

#define DMODEL 768
#define DFC    3072
#define NHEAD  12
#define DHEAD  64
#define BSZ    4
#define SEQ    1024
#define NTOK   (BSZ*SEQ)
#define QKVN   (3*DMODEL)   // 2304

typedef unsigned short u16;
typedef unsigned int   u32;
typedef unsigned long long u64;
typedef __bf16 bf16_t;
typedef bf16_t bf16x8 __attribute__((ext_vector_type(8)));
typedef float  f32x4  __attribute__((ext_vector_type(4)));

__device__ __forceinline__ u16 f2b(float f) {
  u32 u = __builtin_bit_cast(u32, f);
  u = (u + 0x7FFFu + ((u >> 16) & 1u)) >> 16;
  return (u16)u;
}

__device__ __forceinline__ void gload_lds16(const void* g, void* l) {
  __builtin_amdgcn_global_load_lds(
      (const __attribute__((address_space(1))) void*)g,
      (__attribute__((address_space(3))) void*)l, 16, 0, 0);
}

// ---------------- prep kernels ----------------

__global__ __launch_bounds__(256) void cast_f32_bf16(const float* __restrict__ in,
                                                     u16* __restrict__ out, int n4) {
  int i = blockIdx.x * 256 + threadIdx.x;
  if (i >= n4) return;
  float4 v = ((const float4*)in)[i];
  ushort4 o;
  o.x = f2b(v.x); o.y = f2b(v.y); o.z = f2b(v.z); o.w = f2b(v.w);
  ((ushort4*)out)[i] = o;
}

// in: [K][N] f32 -> out: [N][K] bf16
__global__ __launch_bounds__(256) void transpose_cast(const float* __restrict__ in,
                                                      u16* __restrict__ out, int K, int N) {
  __shared__ float tile[32][33];
  int bx = blockIdx.x * 32;  // N dim
  int by = blockIdx.y * 32;  // K dim
  int tx = threadIdx.x, ty = threadIdx.y;
#pragma unroll
  for (int i = 0; i < 4; ++i)
    tile[ty + i*8][tx] = in[(size_t)(by + ty + i*8) * N + bx + tx];
  __syncthreads();
#pragma unroll
  for (int i = 0; i < 4; ++i)
    out[(size_t)(bx + ty + i*8) * K + by + tx] = f2b(tile[tx][ty + i*8]);
}

// mask [B,S,S] int32 -> packed u64 words, word idx = ((b*S+q)*16 + kt), bit k = mask!=0
__global__ __launch_bounds__(256) void pack_mask(const int* __restrict__ mask,
                                                 u64* __restrict__ mp) {
  int w = threadIdx.x >> 6, lane = threadIdx.x & 63;
  int idx = blockIdx.x * 4 + w;
  u64 bal = __ballot(mask[(size_t)idx * 64 + lane] != 0);
  if (lane == 0) mp[idx] = bal;
}

// V columns of QKVM -> VT[b*H+h][d][s]
__global__ __launch_bounds__(256) void build_vt(const u16* __restrict__ QKVM,
                                                u16* __restrict__ VT) {
  __shared__ u16 t[64][72];
  int st = blockIdx.x, h = blockIdx.y, b = blockIdx.z;
  int tid = threadIdx.x;
  const u16* src = QKVM + ((size_t)(b * SEQ + st * 64)) * QKVN + 2 * DMODEL + h * DHEAD;
#pragma unroll
  for (int p = 0; p < 2; ++p) {
    int s = (p * 256 + tid) >> 3, c8 = tid & 7;
    *(uint4*)&t[s][c8 * 8] = *(const uint4*)&src[(size_t)s * QKVN + c8 * 8];
  }
  __syncthreads();
  u16* dst = VT + ((size_t)(b * NHEAD + h) * 64) * SEQ + st * 64;
#pragma unroll
  for (int p = 0; p < 2; ++p) {
    int d = (p * 256 + tid) >> 3, s8 = tid & 7;
    union { uint4 v; u16 s[8]; } o;
#pragma unroll
    for (int j = 0; j < 8; ++j) o.s[j] = t[s8 * 8 + j][d];
    *(uint4*)&dst[(size_t)d * SEQ + s8 * 8] = o.v;
  }
}

// ---------------- GEMM: C[M][N] = A[M][K] (bf16) @ Bt[N][K]^T (bf16) ----------------
// MODE 0: store bf16 | MODE 2: +bias, relu, store bf16 | MODE 4: atomicAdd f32 (split-K)
// LDS 16B slots XOR-swizzled with (row>>1)&3 on global source AND ds_read (involution).
template <int MODE, int SPLIT>
__global__ __launch_bounds__(256) void gemm_bt(const u16* __restrict__ A,
                                               const u16* __restrict__ Bt,
                                               void* __restrict__ Cout,
                                               const float* __restrict__ bias,
                                               int M, int N, int K) {
  __shared__ __align__(16) u16 ldsA[2][128 * 32];
  __shared__ __align__(16) u16 ldsB[2][128 * 32];
  int tid = threadIdx.x;
  int lane = tid & 63, l15 = lane & 15, g = lane >> 4;
  int w = tid >> 6, wm = w >> 1, wn = w & 1;
  int m0 = blockIdx.y * 128, n0 = blockIdx.x * 128;
  int KS = K / SPLIT;
  int k0 = blockIdx.z * KS;
  int NT = KS >> 5;

  f32x4 acc[4][4];
#pragma unroll
  for (int i = 0; i < 4; ++i)
#pragma unroll
    for (int j = 0; j < 4; ++j) acc[i][j] = (f32x4){0.f, 0.f, 0.f, 0.f};

  const u16* gabase = A + (size_t)m0 * K + k0;
  const u16* gbbase = Bt + (size_t)n0 * K + k0;
  int wbase = tid & ~63;
  int lswz = (lane & 3) ^ ((lane >> 3) & 3);  // source-side slot swizzle

  auto stage = [&](int kt, int buf) {
#pragma unroll
    for (int p = 0; p < 2; ++p) {
      int c = p * 256 + tid;
      int row = c >> 2;
      size_t goff = (size_t)row * K + kt * 32 + lswz * 8;
      gload_lds16(gabase + goff, &ldsA[buf][(p * 256 + wbase) * 8]);
      gload_lds16(gbbase + goff, &ldsB[buf][(p * 256 + wbase) * 8]);
    }
  };

  int rswz = (l15 >> 1) & 3;  // read-side swizzle (row>>1)&3 == (l15>>1)&3 here

  stage(0, 0);
  __syncthreads();
  for (int kt = 0; kt < NT; ++kt) {
    int cur = kt & 1;
    if (kt + 1 < NT) stage(kt + 1, cur ^ 1);
    bf16x8 af[4], bfr[4];
#pragma unroll
    for (int i = 0; i < 4; ++i) {
      af[i]  = *(const bf16x8*)&ldsA[cur][(wm * 64 + i * 16 + l15) * 32 + (g ^ rswz) * 8];
      bfr[i] = *(const bf16x8*)&ldsB[cur][(wn * 64 + i * 16 + l15) * 32 + (g ^ rswz) * 8];
    }
#pragma unroll
    for (int i = 0; i < 4; ++i)
#pragma unroll
      for (int j = 0; j < 4; ++j)
        acc[i][j] = __builtin_amdgcn_mfma_f32_16x16x32_bf16(af[i], bfr[j], acc[i][j], 0, 0, 0);
    __syncthreads();
  }

#pragma unroll
  for (int i = 0; i < 4; ++i) {
#pragma unroll
    for (int j = 0; j < 4; ++j) {
#pragma unroll
      for (int r = 0; r < 4; ++r) {
        int row = m0 + wm * 64 + i * 16 + g * 4 + r;
        int col = n0 + wn * 64 + j * 16 + l15;
        float v = acc[i][j][r];
        if (MODE == 2) {
          v += bias[col];
          v = v > 0.f ? v : 0.f;
        }
        if (MODE == 4)
          atomicAdd(&((float*)Cout)[(size_t)row * N + col], v);
        else
          ((u16*)Cout)[(size_t)row * N + col] = f2b(v);
      }
    }
  }
}

// ---------------- attention ----------------
__global__ __launch_bounds__(256) void attn_kernel(const u16* __restrict__ QKVM,
                                                   const u16* __restrict__ VT,
                                                   const u64* __restrict__ MP,
                                                   u16* __restrict__ Om) {
  __shared__ __align__(16) u16 ldsK[2][64 * 64];
  __shared__ __align__(16) u16 ldsV[2][64 * 64];
  __shared__ __align__(16) u16 P_lds[4][16][72];

  int qt = blockIdx.x, h = blockIdx.y, b = blockIdx.z;
  int tid = threadIdx.x, w = tid >> 6, lane = tid & 63;
  int l15 = lane & 15, g = lane >> 4, l7 = lane & 7;
  int q0 = qt * 64 + w * 16;

  const u16* Qb = QKVM + (size_t)(b * SEQ) * QKVN + h * DHEAD;
  const u16* Kb = QKVM + (size_t)(b * SEQ) * QKVN + DMODEL + h * DHEAD;
  const u16* Vb = VT + (size_t)(b * NHEAD + h) * 64 * SEQ;

  bf16x8 qf[2];
  qf[0] = *(const bf16x8*)&Qb[(size_t)(q0 + l15) * QKVN + g * 8];
  qf[1] = *(const bf16x8*)&Qb[(size_t)(q0 + l15) * QKVN + 32 + g * 8];

  int r8 = lane >> 3, sl = lane & 7, slg = sl ^ r8;

  auto stage = [&](int kt, int buf) {
#pragma unroll
    for (int p = 0; p < 2; ++p) {
      int c = p * 4 + w;
      int row = c * 8 + r8;
      gload_lds16(Kb + (size_t)(kt * 64 + row) * QKVN + slg * 8, &ldsK[buf][c * 512]);
      gload_lds16(Vb + (size_t)row * SEQ + kt * 64 + slg * 8, &ldsV[buf][c * 512]);
    }
  };

  f32x4 acc[4];
  float ps[4];
#pragma unroll
  for (int d = 0; d < 4; ++d) acc[d] = (f32x4){0.f, 0.f, 0.f, 0.f};
#pragma unroll
  for (int r = 0; r < 4; ++r) ps[r] = 0.f;

  const float SC2 = 0.41650835f;  // (1/sqrt(12)) * log2(e)

  stage(0, 0);
  __syncthreads();

  for (int kt = 0; kt < SEQ / 64; ++kt) {
    int cur = kt & 1;
    if (kt + 1 < SEQ / 64) stage(kt + 1, cur ^ 1);

    u64 mw[4];
#pragma unroll
    for (int r = 0; r < 4; ++r)
      mw[r] = MP[((size_t)(b * SEQ + q0 + g * 4 + r) << 4) | kt];

    f32x4 s[4];
#pragma unroll
    for (int fn = 0; fn < 4; ++fn) s[fn] = (f32x4){0.f, 0.f, 0.f, 0.f};
#pragma unroll
    for (int kf = 0; kf < 2; ++kf)
#pragma unroll
      for (int fn = 0; fn < 4; ++fn) {
        bf16x8 kfrag = *(const bf16x8*)((const char*)&ldsK[cur][0] +
                         (fn * 16 + l15) * 128 + (((kf * 4 + g) ^ l7) << 4));
        s[fn] = __builtin_amdgcn_mfma_f32_16x16x32_bf16(qf[kf], kfrag, s[fn], 0, 0, 0);
      }

#pragma unroll
    for (int fn = 0; fn < 4; ++fn) {
      u32 hv[4];
#pragma unroll
      for (int r = 0; r < 4; ++r)
        hv[r] = (fn & 2) ? (u32)(mw[r] >> 32) : (u32)mw[r];
      u32 bitpos = ((fn & 1) << 4) + l15;
#pragma unroll
      for (int r = 0; r < 4; ++r) {
        float pe = __builtin_amdgcn_exp2f(s[fn][r] * SC2);
        float p = ((hv[r] >> bitpos) & 1u) ? pe : 0.f;
        ps[r] += p;
        P_lds[w][g * 4 + r][fn * 16 + l15] = f2b(p);
      }
    }

#pragma unroll
    for (int kf2 = 0; kf2 < 2; ++kf2) {
      bf16x8 pf = *(const bf16x8*)((const char*)&P_lds[w][0][0] +
                    l15 * 144 + (kf2 * 32 + g * 8) * 2);
#pragma unroll
      for (int d = 0; d < 4; ++d) {
        bf16x8 vf = *(const bf16x8*)((const char*)&ldsV[cur][0] +
                      (d * 16 + l15) * 128 + (((kf2 * 4 + g) ^ l7) << 4));
        acc[d] = __builtin_amdgcn_mfma_f32_16x16x32_bf16(pf, vf, acc[d], 0, 0, 0);
      }
    }
    __syncthreads();
  }

#pragma unroll
  for (int r = 0; r < 4; ++r) {
#pragma unroll
    for (int off = 1; off < 16; off <<= 1) ps[r] += __shfl_xor(ps[r], off);
    ps[r] = 1.f / ps[r];
  }
#pragma unroll
  for (int d = 0; d < 4; ++d)
#pragma unroll
    for (int r = 0; r < 4; ++r) {
      float o = acc[d][r] * ps[r];
      Om[(size_t)(b * SEQ + q0 + g * 4 + r) * DMODEL + h * DHEAD + d * 16 + l15] = f2b(o);
    }
}

// ---------------- layernorm(a + bias? + res) * g + b ----------------
template <bool WRITE_B16, bool ADDB>
__global__ __launch_bounds__(256) void ln_res(const float* __restrict__ a,
                                              const float* __restrict__ res,
                                              const float* __restrict__ badd,
                                              const float* __restrict__ gam,
                                              const float* __restrict__ bet,
                                              float* __restrict__ of,
                                              u16* __restrict__ ob) {
  int w = threadIdx.x >> 6, lane = threadIdx.x & 63;
  int row = blockIdx.x * 4 + w;
  const float* pa = a + (size_t)row * DMODEL;
  const float* pr = res + (size_t)row * DMODEL;
  float v[12];
  float s = 0.f, s2 = 0.f;
#pragma unroll
  for (int j = 0; j < 12; ++j) {
    int c = lane + j * 64;
    float x = pa[c] + pr[c];
    if (ADDB) x += badd[c];
    v[j] = x; s += x; s2 += x * x;
  }
#pragma unroll
  for (int off = 32; off; off >>= 1) {
    s += __shfl_xor(s, off);
    s2 += __shfl_xor(s2, off);
  }
  float mu = s * (1.f / DMODEL);
  float var = s2 * (1.f / DMODEL) - mu * mu;
  float rs = rsqrtf(var + 1e-5f);
#pragma unroll
  for (int j = 0; j < 12; ++j) {
    int c = lane + j * 64;
    float o = (v[j] - mu) * rs * gam[c] + bet[c];
    of[(size_t)row * DMODEL + c] = o;
    if (WRITE_B16) ob[(size_t)row * DMODEL + c] = f2b(o);
  }
}

// ---------------- launcher ----------------
extern "C" void kernel_launch(void* const* d_in, const int* in_sizes, int n_in,
                              void* d_out, int out_size, void* d_ws, size_t ws_size,
                              hipStream_t stream) {
  const float* x   = (const float*)d_in[0];
  const int*   msk = (const int*)d_in[1];
  const float* WQ  = (const float*)d_in[2];
  const float* WK  = (const float*)d_in[3];
  const float* WV  = (const float*)d_in[4];
  const float* Wfc = (const float*)d_in[5];
  const float* W1  = (const float*)d_in[6];
  const float* b1  = (const float*)d_in[7];
  const float* W2  = (const float*)d_in[8];
  const float* b2  = (const float*)d_in[9];
  const float* g1  = (const float*)d_in[10];
  const float* be1 = (const float*)d_in[11];
  const float* g2  = (const float*)d_in[12];
  const float* be2 = (const float*)d_in[13];
  float* out = (float*)d_out;

  char* ws = (char*)d_ws;
  // static layout (bytes):
  u16*  XB    = (u16*)(ws + 0);         //  6291456  [cast -> QKV; then ATTO: attn -> proj]
  u16*  WQKVT = (u16*)(ws + 6291456);   //  3538944  [-> QKV gemm]
  u16*  WFCT  = (u16*)(ws + 9830400);   //  1179648  [-> proj]
  u16*  W1T   = (u16*)(ws + 11010048);  //  4718592  [-> FFN1]
  u16*  W2T   = (u16*)(ws + 15728640);  //  4718592  [-> FFN2]
  u16*  QKVM  = (u16*)(ws + 20447232);  // 18874368  [QKV -> attn]
  u16*  VT    = (u16*)(ws + 39321600);  //  6291456  [build_vt -> attn]
  u64*  MP    = (u64*)(ws + 45613056);  //   524288  [-> attn]
  float* NAF  = (float*)(ws + 46137344);// 12582912  [ln1 -> ln2]
  u16*  NAB   = (u16*)(ws + 58720256);  //  6291456  [ln1 -> FFN1]
  // overlays:
  u16*   ATTO    = XB;            // attn out (XB dead after QKV gemm)
  float* PROJACC = (float*)QKVM;  // 12.6 MB proj split-K acc (QKVM dead after attn)
  u16*   HMID    = QKVM;          // 25.2 MB FFN1 out (spans QKVM+VT, dead after attn)
  float* LINACC  = (float*)ws;    // 12.6 MB FFN2 acc (XB/WQKVT/WFCT/W1T dead by FFN2)

  cast_f32_bf16<<<dim3((NTOK * DMODEL) / 4 / 256), dim3(256), 0, stream>>>(x, XB, (NTOK * DMODEL) / 4);
  transpose_cast<<<dim3(DMODEL / 32, DMODEL / 32), dim3(32, 8), 0, stream>>>(WQ, WQKVT, DMODEL, DMODEL);
  transpose_cast<<<dim3(DMODEL / 32, DMODEL / 32), dim3(32, 8), 0, stream>>>(WK, WQKVT + (size_t)DMODEL * DMODEL, DMODEL, DMODEL);
  transpose_cast<<<dim3(DMODEL / 32, DMODEL / 32), dim3(32, 8), 0, stream>>>(WV, WQKVT + (size_t)2 * DMODEL * DMODEL, DMODEL, DMODEL);
  transpose_cast<<<dim3(DMODEL / 32, DMODEL / 32), dim3(32, 8), 0, stream>>>(Wfc, WFCT, DMODEL, DMODEL);
  transpose_cast<<<dim3(DFC / 32, DMODEL / 32), dim3(32, 8), 0, stream>>>(W1, W1T, DMODEL, DFC);
  transpose_cast<<<dim3(DMODEL / 32, DFC / 32), dim3(32, 8), 0, stream>>>(W2, W2T, DFC, DMODEL);
  pack_mask<<<dim3(BSZ * SEQ * (SEQ / 64) / 4), dim3(256), 0, stream>>>(msk, MP);

  // QKV projection (fused)
  gemm_bt<0, 1><<<dim3(QKVN / 128, NTOK / 128, 1), dim3(256), 0, stream>>>(XB, WQKVT, QKVM, nullptr, NTOK, QKVN, DMODEL);
  build_vt<<<dim3(SEQ / 64, NHEAD, BSZ), dim3(256), 0, stream>>>(QKVM, VT);
  attn_kernel<<<dim3(SEQ / 64, NHEAD, BSZ), dim3(256), 0, stream>>>(QKVM, VT, MP, ATTO);

  // output projection, split-K=2 atomic f32
  hipMemsetAsync(PROJACC, 0, (size_t)NTOK * DMODEL * 4, stream);
  gemm_bt<4, 2><<<dim3(DMODEL / 128, NTOK / 128, 2), dim3(256), 0, stream>>>(ATTO, WFCT, PROJACC, nullptr, NTOK, DMODEL, DMODEL);
  ln_res<true, false><<<dim3(NTOK / 4), dim3(256), 0, stream>>>(PROJACC, x, nullptr, g1, be1, NAF, NAB);

  // FFN1 (+bias+relu)
  gemm_bt<2, 1><<<dim3(DFC / 128, NTOK / 128, 1), dim3(256), 0, stream>>>(NAB, W1T, HMID, b1, NTOK, DFC, DMODEL);
  // FFN2, split-K=4 atomic f32 (bias b2 added in LN2)
  hipMemsetAsync(LINACC, 0, (size_t)NTOK * DMODEL * 4, stream);
  gemm_bt<4, 4><<<dim3(DMODEL / 128, NTOK / 128, 4), dim3(256), 0, stream>>>(HMID, W2T, LINACC, nullptr, NTOK, DMODEL, DFC);
  ln_res<false, true><<<dim3(NTOK / 4), dim3(256), 0, stream>>>(LINACC, NAF, b2, g2, be2, out, nullptr);

  (void)in_sizes; (void)n_in; (void)out_size; (void)ws_size;
}

// Round 4
// 280.349 us; speedup vs baseline: 1.2217x; 1.2217x over previous
//
#include <hip/hip_runtime.h>
#include <stdint.h>

#define DMODEL 768
#define DFC    3072
#define NHEAD  12
#define DHEAD  64
#define BSZ    4
#define SEQ    1024
#define NTOK   (BSZ*SEQ)
#define QKVN   (3*DMODEL)   // 2304

typedef unsigned short u16;
typedef unsigned int   u32;
typedef unsigned long long u64;
typedef __bf16 bf16_t;
typedef bf16_t bf16x8 __attribute__((ext_vector_type(8)));
typedef float  f32x4  __attribute__((ext_vector_type(4)));

__device__ __forceinline__ u16 f2b(float f) {
  u32 u = __builtin_bit_cast(u32, f);
  u = (u + 0x7FFFu + ((u >> 16) & 1u)) >> 16;
  return (u16)u;
}
__device__ __forceinline__ float b2f(u16 u) {
  return __builtin_bit_cast(float, (u32)u << 16);
}

__device__ __forceinline__ void gload_lds16(const void* g, void* l) {
  __builtin_amdgcn_global_load_lds(
      (const __attribute__((address_space(1))) void*)g,
      (__attribute__((address_space(3))) void*)l, 16, 0, 0);
}

// ---------------- fused prep: cast + 6 weight transposes + mask pack ----------------
// blocks: [0,3072) cast | [3072,5376) 4 square transposes | [5376,7680) W1 |
//         [7680,9984) W2 | [9984,26368) pack_mask
__global__ __launch_bounds__(256) void mega_prep(
    const float* __restrict__ x, u16* __restrict__ XB,
    const float* __restrict__ WQ, const float* __restrict__ WK,
    const float* __restrict__ WV, const float* __restrict__ Wfc,
    const float* __restrict__ W1, const float* __restrict__ W2,
    u16* __restrict__ WQKVT, u16* __restrict__ WFCT,
    u16* __restrict__ W1T, u16* __restrict__ W2T,
    const int* __restrict__ mask, u64* __restrict__ MP) {
  __shared__ float tile[32][33];
  int bid = blockIdx.x, tid = threadIdx.x;

  if (bid < 3072) {  // cast x -> bf16
    int i = bid * 256 + tid;
    float4 v = ((const float4*)x)[i];
    ushort4 o;
    o.x = f2b(v.x); o.y = f2b(v.y); o.z = f2b(v.z); o.w = f2b(v.w);
    ((ushort4*)XB)[i] = o;
    return;
  }
  if (bid >= 9984) {  // pack mask
    int t = bid - 9984;
    int w = tid >> 6, lane = tid & 63;
    int idx = t * 4 + w;
    u64 bal = __ballot(mask[(size_t)idx * 64 + lane] != 0);
    if (lane == 0) MP[idx] = bal;
    return;
  }
  // transposes
  const float* in; u16* outp; int K, N, bx, by;
  if (bid < 5376) {
    int r = bid - 3072, which = r / 576, t = r % 576;
    in = which == 0 ? WQ : which == 1 ? WK : which == 2 ? WV : Wfc;
    outp = which < 3 ? WQKVT + (size_t)which * DMODEL * DMODEL : WFCT;
    K = DMODEL; N = DMODEL; bx = (t % 24) * 32; by = (t / 24) * 32;
  } else if (bid < 7680) {
    int t = bid - 5376;
    in = W1; outp = W1T; K = DMODEL; N = DFC;
    bx = (t % 96) * 32; by = (t / 96) * 32;
  } else {
    int t = bid - 7680;
    in = W2; outp = W2T; K = DFC; N = DMODEL;
    bx = (t % 24) * 32; by = (t / 24) * 32;
  }
  int tx = tid & 31, ty = tid >> 5;
#pragma unroll
  for (int i = 0; i < 4; ++i)
    tile[ty + i * 8][tx] = in[(size_t)(by + ty + i * 8) * N + bx + tx];
  __syncthreads();
#pragma unroll
  for (int i = 0; i < 4; ++i)
    outp[(size_t)(bx + ty + i * 8) * K + by + tx] = f2b(tile[tx][ty + i * 8]);
}

// V columns of QKVM -> VT[b*H+h][d][s]
__global__ __launch_bounds__(256) void build_vt(const u16* __restrict__ QKVM,
                                                u16* __restrict__ VT) {
  __shared__ u16 t[64][72];
  int st = blockIdx.x, h = blockIdx.y, b = blockIdx.z;
  int tid = threadIdx.x;
  const u16* src = QKVM + ((size_t)(b * SEQ + st * 64)) * QKVN + 2 * DMODEL + h * DHEAD;
#pragma unroll
  for (int p = 0; p < 2; ++p) {
    int s = (p * 256 + tid) >> 3, c8 = tid & 7;
    *(uint4*)&t[s][c8 * 8] = *(const uint4*)&src[(size_t)s * QKVN + c8 * 8];
  }
  __syncthreads();
  u16* dst = VT + ((size_t)(b * NHEAD + h) * 64) * SEQ + st * 64;
#pragma unroll
  for (int p = 0; p < 2; ++p) {
    int d = (p * 256 + tid) >> 3, s8 = tid & 7;
    union { uint4 v; u16 s[8]; } o;
#pragma unroll
    for (int j = 0; j < 8; ++j) o.s[j] = t[s8 * 8 + j][d];
    *(uint4*)&dst[(size_t)d * SEQ + s8 * 8] = o.v;
  }
}

// ---------------- GEMM: C[M][N] = A[M][K] (bf16) @ Bt[N][K]^T (bf16) ----------------
// MODE 0: store bf16 | 2: +bias+relu bf16 | 4: f32 partial (z-strided) | 5: bf16 partial (pA/pB)
template <int MODE, int SPLIT>
__global__ __launch_bounds__(256) void gemm_bt(const u16* __restrict__ A,
                                               const u16* __restrict__ Bt,
                                               void* __restrict__ Cout,
                                               const float* __restrict__ bias,
                                               u16* __restrict__ pA, u16* __restrict__ pB,
                                               int M, int N, int K) {
  __shared__ __align__(16) u16 ldsA[2][128 * 32];
  __shared__ __align__(16) u16 ldsB[2][128 * 32];
  int tid = threadIdx.x;
  int lane = tid & 63, l15 = lane & 15, g = lane >> 4;
  int w = tid >> 6, wm = w >> 1, wn = w & 1;
  int m0 = blockIdx.y * 128, n0 = blockIdx.x * 128;
  int KS = K / SPLIT;
  int k0 = blockIdx.z * KS;
  int NT = KS >> 5;

  f32x4 acc[4][4];
#pragma unroll
  for (int i = 0; i < 4; ++i)
#pragma unroll
    for (int j = 0; j < 4; ++j) acc[i][j] = (f32x4){0.f, 0.f, 0.f, 0.f};

  const u16* gabase = A + (size_t)m0 * K + k0;
  const u16* gbbase = Bt + (size_t)n0 * K + k0;
  int wbase = tid & ~63;
  int lswz = (lane & 3) ^ ((lane >> 3) & 3);  // source-side 16B slot swizzle

  auto stage = [&](int kt, int buf) {
#pragma unroll
    for (int p = 0; p < 2; ++p) {
      int c = p * 256 + tid;
      int row = c >> 2;
      size_t goff = (size_t)row * K + kt * 32 + lswz * 8;
      gload_lds16(gabase + goff, &ldsA[buf][(p * 256 + wbase) * 8]);
      gload_lds16(gbbase + goff, &ldsB[buf][(p * 256 + wbase) * 8]);
    }
  };

  int rswz = (l15 >> 1) & 3;  // read-side swizzle

  stage(0, 0);
  __syncthreads();
  for (int kt = 0; kt < NT; ++kt) {
    int cur = kt & 1;
    if (kt + 1 < NT) stage(kt + 1, cur ^ 1);
    bf16x8 af[4], bfr[4];
#pragma unroll
    for (int i = 0; i < 4; ++i) {
      af[i]  = *(const bf16x8*)&ldsA[cur][(wm * 64 + i * 16 + l15) * 32 + (g ^ rswz) * 8];
      bfr[i] = *(const bf16x8*)&ldsB[cur][(wn * 64 + i * 16 + l15) * 32 + (g ^ rswz) * 8];
    }
#pragma unroll
    for (int i = 0; i < 4; ++i)
#pragma unroll
      for (int j = 0; j < 4; ++j)
        acc[i][j] = __builtin_amdgcn_mfma_f32_16x16x32_bf16(af[i], bfr[j], acc[i][j], 0, 0, 0);
    __syncthreads();
  }

  u16* pdst = nullptr;
  if (MODE == 5)
    pdst = ((blockIdx.z & 2) ? pB : pA) + (size_t)(blockIdx.z & 1) * M * N;
#pragma unroll
  for (int i = 0; i < 4; ++i) {
#pragma unroll
    for (int j = 0; j < 4; ++j) {
#pragma unroll
      for (int r = 0; r < 4; ++r) {
        int row = m0 + wm * 64 + i * 16 + g * 4 + r;
        int col = n0 + wn * 64 + j * 16 + l15;
        float v = acc[i][j][r];
        if (MODE == 2) {
          v += bias[col];
          v = v > 0.f ? v : 0.f;
        }
        if (MODE == 0 || MODE == 2)
          ((u16*)Cout)[(size_t)row * N + col] = f2b(v);
        else if (MODE == 4)
          ((float*)Cout)[(size_t)blockIdx.z * M * N + (size_t)row * N + col] = v;
        else
          pdst[(size_t)row * N + col] = f2b(v);
      }
    }
  }
}

// ---------------- attention ----------------
__global__ __launch_bounds__(256) void attn_kernel(const u16* __restrict__ QKVM,
                                                   const u16* __restrict__ VT,
                                                   const u64* __restrict__ MP,
                                                   u16* __restrict__ Om) {
  __shared__ __align__(16) u16 ldsK[2][64 * 64];
  __shared__ __align__(16) u16 ldsV[2][64 * 64];
  __shared__ __align__(16) u16 P_lds[4][16][72];

  int qt = blockIdx.x, h = blockIdx.y, b = blockIdx.z;
  int tid = threadIdx.x, w = tid >> 6, lane = tid & 63;
  int l15 = lane & 15, g = lane >> 4, l7 = lane & 7;
  int q0 = qt * 64 + w * 16;

  const u16* Qb = QKVM + (size_t)(b * SEQ) * QKVN + h * DHEAD;
  const u16* Kb = QKVM + (size_t)(b * SEQ) * QKVN + DMODEL + h * DHEAD;
  const u16* Vb = VT + (size_t)(b * NHEAD + h) * 64 * SEQ;

  bf16x8 qf[2];
  qf[0] = *(const bf16x8*)&Qb[(size_t)(q0 + l15) * QKVN + g * 8];
  qf[1] = *(const bf16x8*)&Qb[(size_t)(q0 + l15) * QKVN + 32 + g * 8];

  int r8 = lane >> 3, sl = lane & 7, slg = sl ^ r8;

  auto stage = [&](int kt, int buf) {
#pragma unroll
    for (int p = 0; p < 2; ++p) {
      int c = p * 4 + w;
      int row = c * 8 + r8;
      gload_lds16(Kb + (size_t)(kt * 64 + row) * QKVN + slg * 8, &ldsK[buf][c * 512]);
      gload_lds16(Vb + (size_t)row * SEQ + kt * 64 + slg * 8, &ldsV[buf][c * 512]);
    }
  };

  f32x4 acc[4];
  float ps[4];
#pragma unroll
  for (int d = 0; d < 4; ++d) acc[d] = (f32x4){0.f, 0.f, 0.f, 0.f};
#pragma unroll
  for (int r = 0; r < 4; ++r) ps[r] = 0.f;

  const float SC2 = 0.41650835f;  // (1/sqrt(12)) * log2(e)

  stage(0, 0);
  __syncthreads();

  for (int kt = 0; kt < SEQ / 64; ++kt) {
    int cur = kt & 1;
    if (kt + 1 < SEQ / 64) stage(kt + 1, cur ^ 1);

    u64 mw[4];
#pragma unroll
    for (int r = 0; r < 4; ++r)
      mw[r] = MP[((size_t)(b * SEQ + q0 + g * 4 + r) << 4) | kt];

    f32x4 s[4];
#pragma unroll
    for (int fn = 0; fn < 4; ++fn) s[fn] = (f32x4){0.f, 0.f, 0.f, 0.f};
#pragma unroll
    for (int kf = 0; kf < 2; ++kf)
#pragma unroll
      for (int fn = 0; fn < 4; ++fn) {
        bf16x8 kfrag = *(const bf16x8*)((const char*)&ldsK[cur][0] +
                         (fn * 16 + l15) * 128 + (((kf * 4 + g) ^ l7) << 4));
        s[fn] = __builtin_amdgcn_mfma_f32_16x16x32_bf16(qf[kf], kfrag, s[fn], 0, 0, 0);
      }

#pragma unroll
    for (int fn = 0; fn < 4; ++fn) {
      u32 hv[4];
#pragma unroll
      for (int r = 0; r < 4; ++r)
        hv[r] = (fn & 2) ? (u32)(mw[r] >> 32) : (u32)mw[r];
      u32 bitpos = ((fn & 1) << 4) + l15;
#pragma unroll
      for (int r = 0; r < 4; ++r) {
        float pe = __builtin_amdgcn_exp2f(s[fn][r] * SC2);
        float p = ((hv[r] >> bitpos) & 1u) ? pe : 0.f;
        ps[r] += p;
        P_lds[w][g * 4 + r][fn * 16 + l15] = f2b(p);
      }
    }

#pragma unroll
    for (int kf2 = 0; kf2 < 2; ++kf2) {
      bf16x8 pf = *(const bf16x8*)((const char*)&P_lds[w][0][0] +
                    l15 * 144 + (kf2 * 32 + g * 8) * 2);
#pragma unroll
      for (int d = 0; d < 4; ++d) {
        bf16x8 vf = *(const bf16x8*)((const char*)&ldsV[cur][0] +
                      (d * 16 + l15) * 128 + (((kf2 * 4 + g) ^ l7) << 4));
        acc[d] = __builtin_amdgcn_mfma_f32_16x16x32_bf16(pf, vf, acc[d], 0, 0, 0);
      }
    }
    __syncthreads();
  }

#pragma unroll
  for (int r = 0; r < 4; ++r) {
#pragma unroll
    for (int off = 1; off < 16; off <<= 1) ps[r] += __shfl_xor(ps[r], off);
    ps[r] = 1.f / ps[r];
  }
#pragma unroll
  for (int d = 0; d < 4; ++d)
#pragma unroll
    for (int r = 0; r < 4; ++r) {
      float o = acc[d][r] * ps[r];
      Om[(size_t)(b * SEQ + q0 + g * 4 + r) * DMODEL + h * DHEAD + d * 16 + l15] = f2b(o);
    }
}

// ---------------- LN1: layernorm(p0+p1+x) ; write f32 + bf16 ----------------
__global__ __launch_bounds__(256) void ln_sum2(const float* __restrict__ parts,
                                               const float* __restrict__ res,
                                               const float* __restrict__ gam,
                                               const float* __restrict__ bet,
                                               float* __restrict__ of,
                                               u16* __restrict__ ob) {
  int w = threadIdx.x >> 6, lane = threadIdx.x & 63;
  int row = blockIdx.x * 4 + w;
  const float* p0 = parts + (size_t)row * DMODEL;
  const float* p1 = parts + (size_t)NTOK * DMODEL + (size_t)row * DMODEL;
  const float* pr = res + (size_t)row * DMODEL;
  float4 v[3];
  float s = 0.f, s2 = 0.f;
#pragma unroll
  for (int j = 0; j < 3; ++j) {
    int c = lane * 4 + j * 256;
    float4 a = *(const float4*)&p0[c];
    float4 b = *(const float4*)&p1[c];
    float4 r = *(const float4*)&pr[c];
    float4 t = {a.x + b.x + r.x, a.y + b.y + r.y, a.z + b.z + r.z, a.w + b.w + r.w};
    v[j] = t;
    s += t.x + t.y + t.z + t.w;
    s2 += t.x * t.x + t.y * t.y + t.z * t.z + t.w * t.w;
  }
#pragma unroll
  for (int off = 32; off; off >>= 1) {
    s += __shfl_xor(s, off);
    s2 += __shfl_xor(s2, off);
  }
  float mu = s * (1.f / DMODEL);
  float var = s2 * (1.f / DMODEL) - mu * mu;
  float rs = rsqrtf(var + 1e-5f);
#pragma unroll
  for (int j = 0; j < 3; ++j) {
    int c = lane * 4 + j * 256;
    float4 gm = *(const float4*)&gam[c];
    float4 bt = *(const float4*)&bet[c];
    float4 o = {(v[j].x - mu) * rs * gm.x + bt.x, (v[j].y - mu) * rs * gm.y + bt.y,
                (v[j].z - mu) * rs * gm.z + bt.z, (v[j].w - mu) * rs * gm.w + bt.w};
    *(float4*)&of[(size_t)row * DMODEL + c] = o;
    ushort4 ub = {f2b(o.x), f2b(o.y), f2b(o.z), f2b(o.w)};
    *(ushort4*)&ob[(size_t)row * DMODEL + c] = ub;
  }
}

// ---------------- LN2: layernorm(sum of 4 bf16 partials + b2 + res) -> f32 out ----------------
__global__ __launch_bounds__(256) void ln_sum4(const u16* __restrict__ pA,
                                               const u16* __restrict__ pB,
                                               const float* __restrict__ res,
                                               const float* __restrict__ badd,
                                               const float* __restrict__ gam,
                                               const float* __restrict__ bet,
                                               float* __restrict__ of) {
  int w = threadIdx.x >> 6, lane = threadIdx.x & 63;
  int row = blockIdx.x * 4 + w;
  size_t ro = (size_t)row * DMODEL;
  const size_t PS = (size_t)NTOK * DMODEL;
  float4 v[3];
  float s = 0.f, s2 = 0.f;
#pragma unroll
  for (int j = 0; j < 3; ++j) {
    int c = lane * 4 + j * 256;
    ushort4 u0 = *(const ushort4*)&pA[ro + c];
    ushort4 u1 = *(const ushort4*)&pA[PS + ro + c];
    ushort4 u2 = *(const ushort4*)&pB[ro + c];
    ushort4 u3 = *(const ushort4*)&pB[PS + ro + c];
    float4 r = *(const float4*)&res[ro + c];
    float4 bb = *(const float4*)&badd[c];
    float4 t = {b2f(u0.x) + b2f(u1.x) + b2f(u2.x) + b2f(u3.x) + r.x + bb.x,
                b2f(u0.y) + b2f(u1.y) + b2f(u2.y) + b2f(u3.y) + r.y + bb.y,
                b2f(u0.z) + b2f(u1.z) + b2f(u2.z) + b2f(u3.z) + r.z + bb.z,
                b2f(u0.w) + b2f(u1.w) + b2f(u2.w) + b2f(u3.w) + r.w + bb.w};
    v[j] = t;
    s += t.x + t.y + t.z + t.w;
    s2 += t.x * t.x + t.y * t.y + t.z * t.z + t.w * t.w;
  }
#pragma unroll
  for (int off = 32; off; off >>= 1) {
    s += __shfl_xor(s, off);
    s2 += __shfl_xor(s2, off);
  }
  float mu = s * (1.f / DMODEL);
  float var = s2 * (1.f / DMODEL) - mu * mu;
  float rs = rsqrtf(var + 1e-5f);
#pragma unroll
  for (int j = 0; j < 3; ++j) {
    int c = lane * 4 + j * 256;
    float4 gm = *(const float4*)&gam[c];
    float4 bt = *(const float4*)&bet[c];
    float4 o = {(v[j].x - mu) * rs * gm.x + bt.x, (v[j].y - mu) * rs * gm.y + bt.y,
                (v[j].z - mu) * rs * gm.z + bt.z, (v[j].w - mu) * rs * gm.w + bt.w};
    *(float4*)&of[ro + c] = o;
  }
}

// ---------------- launcher ----------------
extern "C" void kernel_launch(void* const* d_in, const int* in_sizes, int n_in,
                              void* d_out, int out_size, void* d_ws, size_t ws_size,
                              hipStream_t stream) {
  const float* x   = (const float*)d_in[0];
  const int*   msk = (const int*)d_in[1];
  const float* WQ  = (const float*)d_in[2];
  const float* WK  = (const float*)d_in[3];
  const float* WV  = (const float*)d_in[4];
  const float* Wfc = (const float*)d_in[5];
  const float* W1  = (const float*)d_in[6];
  const float* b1  = (const float*)d_in[7];
  const float* W2  = (const float*)d_in[8];
  const float* b2  = (const float*)d_in[9];
  const float* g1  = (const float*)d_in[10];
  const float* be1 = (const float*)d_in[11];
  const float* g2  = (const float*)d_in[12];
  const float* be2 = (const float*)d_in[13];
  float* out = (float*)d_out;

  char* ws = (char*)d_ws;
  // static layout (byte offsets):
  u16*  XB    = (u16*)(ws + 0);          //  6291456
  u16*  WQKVT = (u16*)(ws + 6291456);    //  3538944
  u16*  WFCT  = (u16*)(ws + 9830400);    //  1179648
  u16*  W1T   = (u16*)(ws + 11010048);   //  4718592
  u16*  W2T   = (u16*)(ws + 15728640);   //  4718592
  u16*  QKVM  = (u16*)(ws + 20447232);   // 18874368
  u16*  VT    = (u16*)(ws + 39321600);   //  6291456
  u64*  MP    = (u64*)(ws + 45613056);   //   524288
  float* NAF  = (float*)(ws + 46137344); // 12582912  [ln1 -> ln2]
  u16*  NAB   = (u16*)(ws + 58720256);   //  6291456  [ln1 -> FFN1]
  // overlays (liveness-checked):
  u16*   ATTO    = XB;                    // attn out (XB dead after QKV gemm)
  float* PROJP   = (float*)QKVM;          // 2x12.58MB f32 proj partials (QKVM+VT dead after attn)
  u16*   HMID    = QKVM;                  // 25.2MB FFN1 out (over QKVM+VT, after ln1)
  u16*   LINPA   = (u16*)(ws + 0);        // FFN2 bf16 partials 0,1 (XB/WQKVT/WFCT dead)
  u16*   LINPB   = (u16*)(ws + 58720256); // FFN2 bf16 partials 2 (over NAB) ,3 (fresh, ends 71.3MB)

  mega_prep<<<dim3(26368), dim3(256), 0, stream>>>(x, XB, WQ, WK, WV, Wfc, W1, W2,
                                                   WQKVT, WFCT, W1T, W2T, msk, MP);

  // QKV projection (fused)
  gemm_bt<0, 1><<<dim3(QKVN / 128, NTOK / 128, 1), dim3(256), 0, stream>>>(
      XB, WQKVT, QKVM, nullptr, nullptr, nullptr, NTOK, QKVN, DMODEL);
  build_vt<<<dim3(SEQ / 64, NHEAD, BSZ), dim3(256), 0, stream>>>(QKVM, VT);
  attn_kernel<<<dim3(SEQ / 64, NHEAD, BSZ), dim3(256), 0, stream>>>(QKVM, VT, MP, ATTO);

  // output projection, split-K=2, f32 partials (plain stores)
  gemm_bt<4, 2><<<dim3(DMODEL / 128, NTOK / 128, 2), dim3(256), 0, stream>>>(
      ATTO, WFCT, PROJP, nullptr, nullptr, nullptr, NTOK, DMODEL, DMODEL);
  ln_sum2<<<dim3(NTOK / 4), dim3(256), 0, stream>>>(PROJP, x, g1, be1, NAF, NAB);

  // FFN1 (+bias+relu)
  gemm_bt<2, 1><<<dim3(DFC / 128, NTOK / 128, 1), dim3(256), 0, stream>>>(
      NAB, W1T, HMID, b1, nullptr, nullptr, NTOK, DFC, DMODEL);
  // FFN2, split-K=4, bf16 partials
  gemm_bt<5, 4><<<dim3(DMODEL / 128, NTOK / 128, 4), dim3(256), 0, stream>>>(
      HMID, W2T, nullptr, nullptr, LINPA, LINPB, NTOK, DMODEL, DFC);
  ln_sum4<<<dim3(NTOK / 4), dim3(256), 0, stream>>>(LINPA, LINPB, NAF, b2, g2, be2, out);

  (void)in_sizes; (void)n_in; (void)out_size; (void)ws_size;
}

// Round 5
// 274.089 us; speedup vs baseline: 1.2496x; 1.0228x over previous
//
#include <hip/hip_runtime.h>
#include <stdint.h>

#define DMODEL 768
#define DFC    3072
#define NHEAD  12
#define DHEAD  64
#define BSZ    4
#define SEQ    1024
#define NTOK   (BSZ*SEQ)
#define QKVN   (3*DMODEL)   // 2304

typedef unsigned short u16;
typedef unsigned int   u32;
typedef unsigned long long u64;
typedef __bf16 bf16_t;
typedef bf16_t bf16x8 __attribute__((ext_vector_type(8)));
typedef bf16_t bf16x4 __attribute__((ext_vector_type(4)));
typedef bf16_t bf16x2 __attribute__((ext_vector_type(2)));
typedef float  f32x4  __attribute__((ext_vector_type(4)));

__device__ __forceinline__ u16 f2b(float f) {  // native RNE cast (v_cvt_pk_bf16_f32)
  __bf16 h = (__bf16)f;
  return __builtin_bit_cast(u16, h);
}
__device__ __forceinline__ float b2f(u16 u) {
  return __builtin_bit_cast(float, (u32)u << 16);
}

__device__ __forceinline__ void gload_lds16(const void* g, void* l) {
  __builtin_amdgcn_global_load_lds(
      (const __attribute__((address_space(1))) void*)g,
      (__attribute__((address_space(3))) void*)l, 16, 0, 0);
}

// ---------------- fused prep: cast + 6 weight transposes + mask pack ----------------
__global__ __launch_bounds__(256) void mega_prep(
    const float* __restrict__ x, u16* __restrict__ XB,
    const float* __restrict__ WQ, const float* __restrict__ WK,
    const float* __restrict__ WV, const float* __restrict__ Wfc,
    const float* __restrict__ W1, const float* __restrict__ W2,
    u16* __restrict__ WQKVT, u16* __restrict__ WFCT,
    u16* __restrict__ W1T, u16* __restrict__ W2T,
    const int* __restrict__ mask, u64* __restrict__ MP) {
  __shared__ float tile[32][33];
  int bid = blockIdx.x, tid = threadIdx.x;

  if (bid < 3072) {  // cast x -> bf16
    int i = bid * 256 + tid;
    float4 v = ((const float4*)x)[i];
    ushort4 o;
    o.x = f2b(v.x); o.y = f2b(v.y); o.z = f2b(v.z); o.w = f2b(v.w);
    ((ushort4*)XB)[i] = o;
    return;
  }
  if (bid >= 9984) {  // pack mask
    int t = bid - 9984;
    int w = tid >> 6, lane = tid & 63;
    int idx = t * 4 + w;
    u64 bal = __ballot(mask[(size_t)idx * 64 + lane] != 0);
    if (lane == 0) MP[idx] = bal;
    return;
  }
  const float* in; u16* outp; int K, N, bx, by;
  if (bid < 5376) {
    int r = bid - 3072, which = r / 576, t = r % 576;
    in = which == 0 ? WQ : which == 1 ? WK : which == 2 ? WV : Wfc;
    outp = which < 3 ? WQKVT + (size_t)which * DMODEL * DMODEL : WFCT;
    K = DMODEL; N = DMODEL; bx = (t % 24) * 32; by = (t / 24) * 32;
  } else if (bid < 7680) {
    int t = bid - 5376;
    in = W1; outp = W1T; K = DMODEL; N = DFC;
    bx = (t % 96) * 32; by = (t / 96) * 32;
  } else {
    int t = bid - 7680;
    in = W2; outp = W2T; K = DFC; N = DMODEL;
    bx = (t % 24) * 32; by = (t / 24) * 32;
  }
  int tx = tid & 31, ty = tid >> 5;
#pragma unroll
  for (int i = 0; i < 4; ++i)
    tile[ty + i * 8][tx] = in[(size_t)(by + ty + i * 8) * N + bx + tx];
  __syncthreads();
#pragma unroll
  for (int i = 0; i < 4; ++i)
    outp[(size_t)(bx + ty + i * 8) * K + by + tx] = f2b(tile[tx][ty + i * 8]);
}

// V columns of QKVM -> VT[b*H+h][d][s]
__global__ __launch_bounds__(256) void build_vt(const u16* __restrict__ QKVM,
                                                u16* __restrict__ VT) {
  __shared__ u16 t[64][72];
  int st = blockIdx.x, h = blockIdx.y, b = blockIdx.z;
  int tid = threadIdx.x;
  const u16* src = QKVM + ((size_t)(b * SEQ + st * 64)) * QKVN + 2 * DMODEL + h * DHEAD;
#pragma unroll
  for (int p = 0; p < 2; ++p) {
    int s = (p * 256 + tid) >> 3, c8 = tid & 7;
    *(uint4*)&t[s][c8 * 8] = *(const uint4*)&src[(size_t)s * QKVN + c8 * 8];
  }
  __syncthreads();
  u16* dst = VT + ((size_t)(b * NHEAD + h) * 64) * SEQ + st * 64;
#pragma unroll
  for (int p = 0; p < 2; ++p) {
    int d = (p * 256 + tid) >> 3, s8 = tid & 7;
    union { uint4 v; u16 s[8]; } o;
#pragma unroll
    for (int j = 0; j < 8; ++j) o.s[j] = t[s8 * 8 + j][d];
    *(uint4*)&dst[(size_t)d * SEQ + s8 * 8] = o.v;
  }
}

// ---------------- GEMM: C[M][N] = A[M][K] (bf16) @ Bt[N][K]^T (bf16) ----------------
// MODE 0: bf16 | 2: +bias+relu bf16 | 4: f32 partial (z-strided) | 5: bf16 partial (pA/pB)
template <int MODE, int SPLIT>
__global__ __launch_bounds__(256) void gemm_bt(const u16* __restrict__ A,
                                               const u16* __restrict__ Bt,
                                               void* __restrict__ Cout,
                                               const float* __restrict__ bias,
                                               u16* __restrict__ pA, u16* __restrict__ pB,
                                               int M, int N, int K) {
  __shared__ __align__(16) u16 ldsA[2][128 * 32];
  __shared__ __align__(16) u16 ldsB[2][128 * 32];
  int tid = threadIdx.x;
  int lane = tid & 63, l15 = lane & 15, g = lane >> 4;
  int w = tid >> 6, wm = w >> 1, wn = w & 1;

  // XCD-bijective block swizzle (all grids here have nwg % 8 == 0)
  int gx = gridDim.x;
  int bid = blockIdx.y * gx + blockIdx.x;
  int nwg = gx * gridDim.y;
  int wgid = ((nwg & 7) == 0) ? ((bid & 7) * (nwg >> 3) + (bid >> 3)) : bid;
  int m0 = (wgid / gx) * 128, n0 = (wgid % gx) * 128;

  int KS = K / SPLIT;
  int k0 = blockIdx.z * KS;
  int NT = KS >> 5;

  f32x4 acc[4][4];
#pragma unroll
  for (int i = 0; i < 4; ++i)
#pragma unroll
    for (int j = 0; j < 4; ++j) acc[i][j] = (f32x4){0.f, 0.f, 0.f, 0.f};

  const u16* gabase = A + (size_t)m0 * K + k0;
  const u16* gbbase = Bt + (size_t)n0 * K + k0;
  int wbase = tid & ~63;
  int lswz = (lane & 3) ^ ((lane >> 3) & 3);  // source-side 16B slot swizzle

  auto stage = [&](int kt, int buf) {
#pragma unroll
    for (int p = 0; p < 2; ++p) {
      int c = p * 256 + tid;
      int row = c >> 2;
      size_t goff = (size_t)row * K + kt * 32 + lswz * 8;
      gload_lds16(gabase + goff, &ldsA[buf][(p * 256 + wbase) * 8]);
      gload_lds16(gbbase + goff, &ldsB[buf][(p * 256 + wbase) * 8]);
    }
  };

  int rswz = (l15 >> 1) & 3;  // read-side swizzle

  stage(0, 0);
  __syncthreads();
  for (int kt = 0; kt < NT; ++kt) {
    int cur = kt & 1;
    if (kt + 1 < NT) stage(kt + 1, cur ^ 1);
    bf16x8 af[4], bfr[4];
#pragma unroll
    for (int i = 0; i < 4; ++i) {
      af[i]  = *(const bf16x8*)&ldsA[cur][(wm * 64 + i * 16 + l15) * 32 + (g ^ rswz) * 8];
      bfr[i] = *(const bf16x8*)&ldsB[cur][(wn * 64 + i * 16 + l15) * 32 + (g ^ rswz) * 8];
    }
#pragma unroll
    for (int i = 0; i < 4; ++i)
#pragma unroll
      for (int j = 0; j < 4; ++j)
        acc[i][j] = __builtin_amdgcn_mfma_f32_16x16x32_bf16(af[i], bfr[j], acc[i][j], 0, 0, 0);
    __syncthreads();
  }

  u16* pdst = nullptr;
  if (MODE == 5)
    pdst = ((blockIdx.z & 2) ? pB : pA) + (size_t)(blockIdx.z & 1) * M * N;
#pragma unroll
  for (int i = 0; i < 4; ++i) {
#pragma unroll
    for (int j = 0; j < 4; ++j) {
#pragma unroll
      for (int r = 0; r < 4; ++r) {
        int row = m0 + wm * 64 + i * 16 + g * 4 + r;
        int col = n0 + wn * 64 + j * 16 + l15;
        float v = acc[i][j][r];
        if (MODE == 2) {
          v += bias[col];
          v = v > 0.f ? v : 0.f;
        }
        if (MODE == 0 || MODE == 2)
          ((u16*)Cout)[(size_t)row * N + col] = f2b(v);
        else if (MODE == 4)
          ((float*)Cout)[(size_t)blockIdx.z * M * N + (size_t)row * N + col] = v;
        else
          pdst[(size_t)row * N + col] = f2b(v);
      }
    }
  }
}

// ---------------- attention ----------------
// 1D grid 768 blocks, XCD-bijective: the 16 qt-blocks of a (b,h) share one XCD's L2.
__global__ __launch_bounds__(256) void attn_kernel(const u16* __restrict__ QKVM,
                                                   const u16* __restrict__ VT,
                                                   const u64* __restrict__ MP,
                                                   u16* __restrict__ Om) {
  __shared__ __align__(16) u16 ldsK[2][64 * 64];
  __shared__ __align__(16) u16 ldsV[2][64 * 64];
  __shared__ __align__(16) u16 Pt[4][64 * 16];  // per-wave P^T [key][q]

  int bid = blockIdx.x;
  int logical = (bid & 7) * 96 + (bid >> 3);
  int qt = logical & 15, hb = logical >> 4;
  int h = hb % NHEAD, b = hb / NHEAD;

  int tid = threadIdx.x, w = tid >> 6, lane = tid & 63;
  int l15 = lane & 15, g = lane >> 4;
  int q0 = qt * 64 + w * 16;

  const u16* Qb = QKVM + (size_t)(b * SEQ) * QKVN + h * DHEAD;
  const u16* Kb = QKVM + (size_t)(b * SEQ) * QKVN + DMODEL + h * DHEAD;
  const u16* Vb = VT + (size_t)(b * NHEAD + h) * 64 * SEQ;

  bf16x8 qf[2];
  qf[0] = *(const bf16x8*)&Qb[(size_t)(q0 + l15) * QKVN + g * 8];
  qf[1] = *(const bf16x8*)&Qb[(size_t)(q0 + l15) * QKVN + 32 + g * 8];

  int r8 = lane >> 3, sl = lane & 7, slg = sl ^ r8;

  auto stage = [&](int kt, int buf) {
#pragma unroll
    for (int p = 0; p < 2; ++p) {
      int c = p * 4 + w;
      int row = c * 8 + r8;
      gload_lds16(Kb + (size_t)(kt * 64 + row) * QKVN + slg * 8, &ldsK[buf][c * 512]);
      gload_lds16(Vb + (size_t)row * SEQ + kt * 64 + slg * 8, &ldsV[buf][c * 512]);
    }
  };

  f32x4 acc[4];
  float ps[4];
#pragma unroll
  for (int d = 0; d < 4; ++d) acc[d] = (f32x4){0.f, 0.f, 0.f, 0.f};
#pragma unroll
  for (int r = 0; r < 4; ++r) ps[r] = 0.f;

  const float SC2 = 0.41650835f;  // (1/sqrt(12)) * log2(e)
  u32 pbase = (u32)(uintptr_t)(__attribute__((address_space(3))) void*)&Pt[w][0]
              + (u32)lane * 8u;
  int l7s = l15 & 7;

  stage(0, 0);
  __syncthreads();

  for (int kt = 0; kt < SEQ / 64; ++kt) {
    int cur = kt & 1;
    if (kt + 1 < SEQ / 64) stage(kt + 1, cur ^ 1);

    u64 mw[4];
#pragma unroll
    for (int r = 0; r < 4; ++r)
      mw[r] = MP[((size_t)(b * SEQ + q0 + g * 4 + r) << 4) | kt];

    // V fragments (b64, swizzle-aware), k-map: elem e -> k = kf2*32 + half*16 + g*4 + e
    bf16x4 vh[2][4][2];
#pragma unroll
    for (int kf2 = 0; kf2 < 2; ++kf2)
#pragma unroll
      for (int d = 0; d < 4; ++d)
#pragma unroll
        for (int hf = 0; hf < 2; ++hf) {
          int slot = (kf2 * 4 + hf * 2 + (g >> 1)) ^ l7s;
          vh[kf2][d][hf] = *(const bf16x4*)&ldsV[cur][(d * 16 + l15) * 64 + slot * 8 + (g & 1) * 4];
        }

    // S = Q K^T (swizzled LDS reads)
    f32x4 s[4];
#pragma unroll
    for (int fn = 0; fn < 4; ++fn) s[fn] = (f32x4){0.f, 0.f, 0.f, 0.f};
#pragma unroll
    for (int kf = 0; kf < 2; ++kf)
#pragma unroll
      for (int fn = 0; fn < 4; ++fn) {
        bf16x8 kfrag = *(const bf16x8*)((const char*)&ldsK[cur][0] +
                         (fn * 16 + l15) * 128 + (((kf * 4 + g) ^ l7s) << 4));
        s[fn] = __builtin_amdgcn_mfma_f32_16x16x32_bf16(qf[kf], kfrag, s[fn], 0, 0, 0);
      }

    // softmax-lite + pack P^T[key][q]: one b64 write per fn
#pragma unroll
    for (int fn = 0; fn < 4; ++fn) {
      u32 bitpos = ((fn & 1) << 4) + l15;
      float p[4];
#pragma unroll
      for (int r = 0; r < 4; ++r) {
        u32 hv = (fn & 2) ? (u32)(mw[r] >> 32) : (u32)mw[r];
        float pe = __builtin_amdgcn_exp2f(s[fn][r] * SC2);
        p[r] = ((hv >> bitpos) & 1u) ? pe : 0.f;
        ps[r] += p[r];
      }
      bf16x2 h0 = {(__bf16)p[0], (__bf16)p[1]};
      bf16x2 h1 = {(__bf16)p[2], (__bf16)p[3]};
      *(uint2*)&Pt[w][(fn * 16 + l15) * 16 + g * 4] =
          make_uint2(__builtin_bit_cast(u32, h0), __builtin_bit_cast(u32, h1));
    }

    // drain P writes, then HW transpose-read A fragments
    asm volatile("s_waitcnt lgkmcnt(0)" ::: "memory");
    __builtin_amdgcn_sched_barrier(0);
    uint2 t0, t1, t2, t3;
    asm volatile("ds_read_b64_tr_b16 %0, %1 offset:0"    : "=v"(t0) : "v"(pbase) : "memory");
    asm volatile("ds_read_b64_tr_b16 %0, %1 offset:512"  : "=v"(t1) : "v"(pbase) : "memory");
    asm volatile("ds_read_b64_tr_b16 %0, %1 offset:1024" : "=v"(t2) : "v"(pbase) : "memory");
    asm volatile("ds_read_b64_tr_b16 %0, %1 offset:1536" : "=v"(t3) : "v"(pbase) : "memory");
    asm volatile("s_waitcnt lgkmcnt(0)" ::: "memory");
    __builtin_amdgcn_sched_barrier(0);

    union { uint2 u2[2]; bf16x8 v; } pa0, pa1;
    pa0.u2[0] = t0; pa0.u2[1] = t1;  // k = g*4+e | 16+g*4+e
    pa1.u2[0] = t2; pa1.u2[1] = t3;  // k = 32+.. | 48+..

#pragma unroll
    for (int kf2 = 0; kf2 < 2; ++kf2) {
      bf16x8 pa = kf2 ? pa1.v : pa0.v;
#pragma unroll
      for (int d = 0; d < 4; ++d) {
        union { bf16x4 h[2]; bf16x8 v; } vf;
        vf.h[0] = vh[kf2][d][0]; vf.h[1] = vh[kf2][d][1];
        acc[d] = __builtin_amdgcn_mfma_f32_16x16x32_bf16(pa, vf.v, acc[d], 0, 0, 0);
      }
    }
    __syncthreads();  // drains prefetch; protects K/V dbuf
  }

#pragma unroll
  for (int r = 0; r < 4; ++r) {
#pragma unroll
    for (int off = 1; off < 16; off <<= 1) ps[r] += __shfl_xor(ps[r], off);
    ps[r] = 1.f / ps[r];
  }
#pragma unroll
  for (int d = 0; d < 4; ++d)
#pragma unroll
    for (int r = 0; r < 4; ++r) {
      float o = acc[d][r] * ps[r];
      Om[(size_t)(b * SEQ + q0 + g * 4 + r) * DMODEL + h * DHEAD + d * 16 + l15] = f2b(o);
    }
}

// ---------------- LN1: layernorm(p0+p1+x) ; write f32 + bf16 ----------------
__global__ __launch_bounds__(256) void ln_sum2(const float* __restrict__ parts,
                                               const float* __restrict__ res,
                                               const float* __restrict__ gam,
                                               const float* __restrict__ bet,
                                               float* __restrict__ of,
                                               u16* __restrict__ ob) {
  int w = threadIdx.x >> 6, lane = threadIdx.x & 63;
  int row = blockIdx.x * 4 + w;
  const float* p0 = parts + (size_t)row * DMODEL;
  const float* p1 = parts + (size_t)NTOK * DMODEL + (size_t)row * DMODEL;
  const float* pr = res + (size_t)row * DMODEL;
  float4 v[3];
  float s = 0.f, s2 = 0.f;
#pragma unroll
  for (int j = 0; j < 3; ++j) {
    int c = lane * 4 + j * 256;
    float4 a = *(const float4*)&p0[c];
    float4 b = *(const float4*)&p1[c];
    float4 r = *(const float4*)&pr[c];
    float4 t = {a.x + b.x + r.x, a.y + b.y + r.y, a.z + b.z + r.z, a.w + b.w + r.w};
    v[j] = t;
    s += t.x + t.y + t.z + t.w;
    s2 += t.x * t.x + t.y * t.y + t.z * t.z + t.w * t.w;
  }
#pragma unroll
  for (int off = 32; off; off >>= 1) {
    s += __shfl_xor(s, off);
    s2 += __shfl_xor(s2, off);
  }
  float mu = s * (1.f / DMODEL);
  float var = s2 * (1.f / DMODEL) - mu * mu;
  float rs = rsqrtf(var + 1e-5f);
#pragma unroll
  for (int j = 0; j < 3; ++j) {
    int c = lane * 4 + j * 256;
    float4 gm = *(const float4*)&gam[c];
    float4 bt = *(const float4*)&bet[c];
    float4 o = {(v[j].x - mu) * rs * gm.x + bt.x, (v[j].y - mu) * rs * gm.y + bt.y,
                (v[j].z - mu) * rs * gm.z + bt.z, (v[j].w - mu) * rs * gm.w + bt.w};
    *(float4*)&of[(size_t)row * DMODEL + c] = o;
    ushort4 ub = {f2b(o.x), f2b(o.y), f2b(o.z), f2b(o.w)};
    *(ushort4*)&ob[(size_t)row * DMODEL + c] = ub;
  }
}

// ---------------- LN2: layernorm(4 bf16 partials + b2 + res) -> f32 out ----------------
__global__ __launch_bounds__(256) void ln_sum4(const u16* __restrict__ pA,
                                               const u16* __restrict__ pB,
                                               const float* __restrict__ res,
                                               const float* __restrict__ badd,
                                               const float* __restrict__ gam,
                                               const float* __restrict__ bet,
                                               float* __restrict__ of) {
  int w = threadIdx.x >> 6, lane = threadIdx.x & 63;
  int row = blockIdx.x * 4 + w;
  size_t ro = (size_t)row * DMODEL;
  const size_t PS = (size_t)NTOK * DMODEL;
  float4 v[3];
  float s = 0.f, s2 = 0.f;
#pragma unroll
  for (int j = 0; j < 3; ++j) {
    int c = lane * 4 + j * 256;
    ushort4 u0 = *(const ushort4*)&pA[ro + c];
    ushort4 u1 = *(const ushort4*)&pA[PS + ro + c];
    ushort4 u2 = *(const ushort4*)&pB[ro + c];
    ushort4 u3 = *(const ushort4*)&pB[PS + ro + c];
    float4 r = *(const float4*)&res[ro + c];
    float4 bb = *(const float4*)&badd[c];
    float4 t = {b2f(u0.x) + b2f(u1.x) + b2f(u2.x) + b2f(u3.x) + r.x + bb.x,
                b2f(u0.y) + b2f(u1.y) + b2f(u2.y) + b2f(u3.y) + r.y + bb.y,
                b2f(u0.z) + b2f(u1.z) + b2f(u2.z) + b2f(u3.z) + r.z + bb.z,
                b2f(u0.w) + b2f(u1.w) + b2f(u2.w) + b2f(u3.w) + r.w + bb.w};
    v[j] = t;
    s += t.x + t.y + t.z + t.w;
    s2 += t.x * t.x + t.y * t.y + t.z * t.z + t.w * t.w;
  }
#pragma unroll
  for (int off = 32; off; off >>= 1) {
    s += __shfl_xor(s, off);
    s2 += __shfl_xor(s2, off);
  }
  float mu = s * (1.f / DMODEL);
  float var = s2 * (1.f / DMODEL) - mu * mu;
  float rs = rsqrtf(var + 1e-5f);
#pragma unroll
  for (int j = 0; j < 3; ++j) {
    int c = lane * 4 + j * 256;
    float4 gm = *(const float4*)&gam[c];
    float4 bt = *(const float4*)&bet[c];
    float4 o = {(v[j].x - mu) * rs * gm.x + bt.x, (v[j].y - mu) * rs * gm.y + bt.y,
                (v[j].z - mu) * rs * gm.z + bt.z, (v[j].w - mu) * rs * gm.w + bt.w};
    *(float4*)&of[ro + c] = o;
  }
}

// ---------------- launcher ----------------
extern "C" void kernel_launch(void* const* d_in, const int* in_sizes, int n_in,
                              void* d_out, int out_size, void* d_ws, size_t ws_size,
                              hipStream_t stream) {
  const float* x   = (const float*)d_in[0];
  const int*   msk = (const int*)d_in[1];
  const float* WQ  = (const float*)d_in[2];
  const float* WK  = (const float*)d_in[3];
  const float* WV  = (const float*)d_in[4];
  const float* Wfc = (const float*)d_in[5];
  const float* W1  = (const float*)d_in[6];
  const float* b1  = (const float*)d_in[7];
  const float* W2  = (const float*)d_in[8];
  const float* b2  = (const float*)d_in[9];
  const float* g1  = (const float*)d_in[10];
  const float* be1 = (const float*)d_in[11];
  const float* g2  = (const float*)d_in[12];
  const float* be2 = (const float*)d_in[13];
  float* out = (float*)d_out;

  char* ws = (char*)d_ws;
  u16*  XB    = (u16*)(ws + 0);          //  6291456
  u16*  WQKVT = (u16*)(ws + 6291456);    //  3538944
  u16*  WFCT  = (u16*)(ws + 9830400);    //  1179648
  u16*  W1T   = (u16*)(ws + 11010048);   //  4718592
  u16*  W2T   = (u16*)(ws + 15728640);   //  4718592
  u16*  QKVM  = (u16*)(ws + 20447232);   // 18874368
  u16*  VT    = (u16*)(ws + 39321600);   //  6291456
  u64*  MP    = (u64*)(ws + 45613056);   //   524288
  float* NAF  = (float*)(ws + 46137344); // 12582912
  u16*  NAB   = (u16*)(ws + 58720256);   //  6291456
  // overlays (liveness-checked):
  u16*   ATTO    = XB;
  float* PROJP   = (float*)QKVM;
  u16*   HMID    = QKVM;
  u16*   LINPA   = (u16*)(ws + 0);
  u16*   LINPB   = (u16*)(ws + 58720256);

  mega_prep<<<dim3(26368), dim3(256), 0, stream>>>(x, XB, WQ, WK, WV, Wfc, W1, W2,
                                                   WQKVT, WFCT, W1T, W2T, msk, MP);

  gemm_bt<0, 1><<<dim3(QKVN / 128, NTOK / 128, 1), dim3(256), 0, stream>>>(
      XB, WQKVT, QKVM, nullptr, nullptr, nullptr, NTOK, QKVN, DMODEL);
  build_vt<<<dim3(SEQ / 64, NHEAD, BSZ), dim3(256), 0, stream>>>(QKVM, VT);
  attn_kernel<<<dim3(BSZ * NHEAD * (SEQ / 64)), dim3(256), 0, stream>>>(QKVM, VT, MP, ATTO);

  gemm_bt<4, 2><<<dim3(DMODEL / 128, NTOK / 128, 2), dim3(256), 0, stream>>>(
      ATTO, WFCT, PROJP, nullptr, nullptr, nullptr, NTOK, DMODEL, DMODEL);
  ln_sum2<<<dim3(NTOK / 4), dim3(256), 0, stream>>>(PROJP, x, g1, be1, NAF, NAB);

  gemm_bt<2, 1><<<dim3(DFC / 128, NTOK / 128, 1), dim3(256), 0, stream>>>(
      NAB, W1T, HMID, b1, nullptr, nullptr, NTOK, DFC, DMODEL);
  gemm_bt<5, 4><<<dim3(DMODEL / 128, NTOK / 128, 4), dim3(256), 0, stream>>>(
      HMID, W2T, nullptr, nullptr, LINPA, LINPB, NTOK, DMODEL, DFC);
  ln_sum4<<<dim3(NTOK / 4), dim3(256), 0, stream>>>(LINPA, LINPB, NAF, b2, g2, be2, out);

  (void)in_sizes; (void)n_in; (void)out_size; (void)ws_size;
}